// Round 7
// baseline (170.926 us; speedup 1.0000x reference)
//
#include <hip/hip_runtime.h>
#include <hip/hip_fp16.h>

// GCN Q-network: two GCNConv(64->64)+ReLU, then FC(64->8).
// out[v] = dinv[v]*(g[v] + sum_{u->v} g[u]) + b,  g[u] = dinv[u]*(X@W)[u]
// All intermediates fp16 (halves gather bytes); gather accumulation via
// v_fma_mix_f32 (1 VALU op per feature instead of cvt+add).
// CSR via bucket partition (512 nodes/bucket), no fp32 atomics.

#define F 64
#define NACT 8
#define BSH 9              // 512 nodes per bucket
#define BNODES 512
#define CAP 10240          // slab capacity per bucket (mean ~8192, sigma ~90)
#define EPB 2048           // edges per scatterE block (256 thr x 8)

// init flag/cursor + sampled dtype detect: int64 edges (values < 2^31) have
// every odd 32-bit word zero; 8192 sampled words of int32 edge data being all
// zero has probability ~0.
__global__ __launch_bounds__(256) void k_init(const unsigned int* __restrict__ w,
    int* flag, int* cursor, int E) {
  if (threadIdx.x == 0) *flag = 1;
  cursor[threadIdx.x] = 0;
  __syncthreads();
  int bad = 0;
  for (int i = threadIdx.x; i < 8192; i += 256) {
    if (i < E && w[2 * i + 1] != 0u) bad = 1;
  }
  if (bad) atomicAnd(flag, 0);
}

__device__ __forceinline__ int edge_row(const unsigned int* w, int flag, int e, int E) {
  return flag ? (int)w[2 * e] : (int)w[e];
}
__device__ __forceinline__ int edge_col(const unsigned int* w, int flag, int e, int E) {
  return flag ? (int)w[2 * E + 2 * e] : (int)w[E + e];
}

// Partition edges into dst-buckets. Packed word: src | (dstLocal << 17).
__global__ __launch_bounds__(256) void k_scatterE(const unsigned int* __restrict__ w,
    const int* __restrict__ flag, int* __restrict__ cursor, unsigned int* __restrict__ slab, int E) {
  __shared__ int hist[256];
  __shared__ int base[256];
  const int tid = threadIdx.x;
  const int fl = *flag;
  hist[tid] = 0;
  __syncthreads();
  int pk[8], bb[8], lr[8];
  const int e0 = blockIdx.x * EPB;
#pragma unroll 8
  for (int j = 0; j < 8; ++j) {
    int e = e0 + j * 256 + tid;
    bb[j] = -1;
    if (e < E) {
      int c = edge_col(w, fl, e, E);
      int s = edge_row(w, fl, e, E);
      int b = c >> BSH;
      pk[j] = (unsigned)s | ((unsigned)(c & (BNODES - 1)) << 17);
      bb[j] = b;
      lr[j] = atomicAdd(&hist[b], 1);
    }
  }
  __syncthreads();
  int h = hist[tid];
  if (h > 0) base[tid] = atomicAdd(&cursor[tid], h);
  __syncthreads();
#pragma unroll 8
  for (int j = 0; j < 8; ++j) {
    if (bb[j] >= 0) {
      slab[(size_t)bb[j] * CAP + base[bb[j]] + lr[j]] = (unsigned)pk[j];
    }
  }
}

// Exclusive scan of per-bucket counts -> bucketBase; csr_off[n] = E.
__global__ __launch_bounds__(64) void k_slabscan(const int* __restrict__ cursor,
    int* __restrict__ bucketBase, int* __restrict__ csr_off, int NB, int n, int E) {
  int t = threadIdx.x;
  int per = (NB + 63) / 64;
  int base = t * per;
  int local = 0;
  for (int i = 0; i < per; ++i) if (base + i < NB) local += cursor[base + i];
  int inc = local;
  for (int off = 1; off < 64; off <<= 1) {
    int vv = __shfl_up(inc, off);
    if (t >= off) inc += vv;
  }
  int run = inc - local;
  for (int i = 0; i < per; ++i) if (base + i < NB) { bucketBase[base + i] = run; run += cursor[base + i]; }
  if (t == 63) { bucketBase[NB] = inc; csr_off[n] = E; }
}

// One block per bucket: LDS count -> scan -> dinv, csr_off, dst-sorted csr_src.
__global__ __launch_bounds__(256) void k_bucketcsr(const unsigned int* __restrict__ slab,
    const int* __restrict__ bucketBase, int* __restrict__ csr_off, float* __restrict__ dinv,
    int* __restrict__ csr_src, int n) {
  __shared__ int cnt[BNODES];
  __shared__ int off[BNODES];
  __shared__ int sA[256], sB[256];
  const int tid = threadIdx.x;
  const int b = blockIdx.x;
  const int csrbeg = bucketBase[b];
  const int cntb = bucketBase[b + 1] - csrbeg;
  const unsigned int* sl = &slab[(size_t)b * CAP];
  cnt[tid] = 0;
  cnt[tid + 256] = 0;
  __syncthreads();
  for (int i = tid; i < cntb; i += 256) {
    atomicAdd(&cnt[sl[i] >> 17], 1);
  }
  __syncthreads();
  int c0 = cnt[2 * tid], c1 = cnt[2 * tid + 1];
  int p = c0 + c1;
  sA[tid] = p;
  __syncthreads();
  int* srcb = sA;
  int* dstb = sB;
  for (int o = 1; o < 256; o <<= 1) {
    int v = srcb[tid];
    if (tid >= o) v += srcb[tid - o];
    __syncthreads();
    dstb[tid] = v;
    __syncthreads();
    int* t2 = srcb; srcb = dstb; dstb = t2;
  }
  int ex2 = srcb[tid] - p;
  off[2 * tid] = ex2;
  off[2 * tid + 1] = ex2 + c0;
  __syncthreads();
  int v0 = (b << BSH) + 2 * tid;
  if (v0 < n) { csr_off[v0] = csrbeg + off[2 * tid]; dinv[v0] = rsqrtf((float)(c0 + 1)); }
  if (v0 + 1 < n) { csr_off[v0 + 1] = csrbeg + off[2 * tid + 1]; dinv[v0 + 1] = rsqrtf((float)(c1 + 1)); }
  __syncthreads();
  for (int i = tid; i < cntb; i += 256) {
    unsigned int pk = sl[i];
    int dl = pk >> 17;
    int pos = atomicAdd(&off[dl], 1);
    csr_src[csrbeg + pos] = (int)(pk & 0x1FFFFu);
  }
}

__device__ __forceinline__ ushort4 packh4(float a, float b, float c, float d) {
  ushort4 r;
  r.x = __half_as_ushort(__float2half_rn(a));
  r.y = __half_as_ushort(__float2half_rn(b));
  r.z = __half_as_ushort(__float2half_rn(c));
  r.w = __half_as_ushort(__float2half_rn(d));
  return r;
}

// a[j] += f32(g.h16[j]) via v_fma_mix_f32 (one VALU op per feature; exact
// f16->f32 promotion, fp32 accumulate -- same rounding as cvt+add).
__device__ __forceinline__ void accmix(float* a, uint4 g) {
  float one = 1.0f;
  asm volatile(
    "v_fma_mix_f32 %0, %9, %8, %0 op_sel:[0,0,0] op_sel_hi:[1,0,0]\n\t"
    "v_fma_mix_f32 %1, %9, %8, %1 op_sel:[1,0,0] op_sel_hi:[1,0,0]\n\t"
    "v_fma_mix_f32 %2, %10, %8, %2 op_sel:[0,0,0] op_sel_hi:[1,0,0]\n\t"
    "v_fma_mix_f32 %3, %10, %8, %3 op_sel:[1,0,0] op_sel_hi:[1,0,0]\n\t"
    "v_fma_mix_f32 %4, %11, %8, %4 op_sel:[0,0,0] op_sel_hi:[1,0,0]\n\t"
    "v_fma_mix_f32 %5, %11, %8, %5 op_sel:[1,0,0] op_sel_hi:[1,0,0]\n\t"
    "v_fma_mix_f32 %6, %12, %8, %6 op_sel:[0,0,0] op_sel_hi:[1,0,0]\n\t"
    "v_fma_mix_f32 %7, %12, %8, %7 op_sel:[1,0,0] op_sel_hi:[1,0,0]"
    : "+v"(a[0]), "+v"(a[1]), "+v"(a[2]), "+v"(a[3]),
      "+v"(a[4]), "+v"(a[5]), "+v"(a[6]), "+v"(a[7])
    : "v"(one), "v"(g.x), "v"(g.y), "v"(g.z), "v"(g.w));
}

// 8-deep unrolled CSR gather of fp16 rows into fp32 acc a[8].
__device__ __forceinline__ void gather8(const uint4* __restrict__ Gv,
    const int* __restrict__ csr_src, int beg, int end, int l, float* a) {
  int j = beg;
  for (; j + 8 <= end; j += 8) {
    uint4 g0 = Gv[(size_t)csr_src[j + 0] * 8 + l];
    uint4 g1 = Gv[(size_t)csr_src[j + 1] * 8 + l];
    uint4 g2 = Gv[(size_t)csr_src[j + 2] * 8 + l];
    uint4 g3 = Gv[(size_t)csr_src[j + 3] * 8 + l];
    uint4 g4 = Gv[(size_t)csr_src[j + 4] * 8 + l];
    uint4 g5 = Gv[(size_t)csr_src[j + 5] * 8 + l];
    uint4 g6 = Gv[(size_t)csr_src[j + 6] * 8 + l];
    uint4 g7 = Gv[(size_t)csr_src[j + 7] * 8 + l];
    accmix(a, g0); accmix(a, g1); accmix(a, g2); accmix(a, g3);
    accmix(a, g4); accmix(a, g5); accmix(a, g6); accmix(a, g7);
  }
  for (; j + 4 <= end; j += 4) {
    uint4 g0 = Gv[(size_t)csr_src[j + 0] * 8 + l];
    uint4 g1 = Gv[(size_t)csr_src[j + 1] * 8 + l];
    uint4 g2 = Gv[(size_t)csr_src[j + 2] * 8 + l];
    uint4 g3 = Gv[(size_t)csr_src[j + 3] * 8 + l];
    accmix(a, g0); accmix(a, g1); accmix(a, g2); accmix(a, g3);
  }
  for (; j < end; ++j) accmix(a, Gv[(size_t)csr_src[j] * 8 + l]);
}

// ---- Gh = fp16(dinv .* (X @ W)), X fp32; 64x64 tile, 4x4 reg tile ----
__global__ __launch_bounds__(256) void k_gemm_h(const float* __restrict__ X, const float* __restrict__ W,
    const float* __restrict__ dinv, unsigned short* __restrict__ Gh, int n) {
  __shared__ float xst[F * 68];  // [k][row], stride 68
  __shared__ float wsh[F * F];   // [k][col]
  const int tid = threadIdx.x;
  const int row0 = blockIdx.x * 64;
  for (int i = tid * 4; i < F * F; i += 1024)
    *(float4*)&wsh[i] = *(const float4*)&W[i];
  for (int i = tid * 4; i < 64 * F; i += 1024) {
    int r = i >> 6, k = i & 63;
    float4 v = make_float4(0.f, 0.f, 0.f, 0.f);
    if (row0 + r < n) v = *(const float4*)&X[(size_t)(row0 + r) * F + k];
    xst[(k + 0) * 68 + r] = v.x;
    xst[(k + 1) * 68 + r] = v.y;
    xst[(k + 2) * 68 + r] = v.z;
    xst[(k + 3) * 68 + r] = v.w;
  }
  __syncthreads();
  const int tc = tid & 15;
  const int tr = tid >> 4;
  float a00 = 0.f, a01 = 0.f, a02 = 0.f, a03 = 0.f;
  float a10 = 0.f, a11 = 0.f, a12 = 0.f, a13 = 0.f;
  float a20 = 0.f, a21 = 0.f, a22 = 0.f, a23 = 0.f;
  float a30 = 0.f, a31 = 0.f, a32 = 0.f, a33 = 0.f;
  const float* xp = &xst[tr * 4];
  const float* wp = &wsh[tc * 4];
#pragma unroll 8
  for (int k = 0; k < F; ++k) {
    float4 xv = *(const float4*)&xp[k * 68];
    float4 wv = *(const float4*)&wp[k * F];
    a00 = fmaf(xv.x, wv.x, a00); a01 = fmaf(xv.x, wv.y, a01);
    a02 = fmaf(xv.x, wv.z, a02); a03 = fmaf(xv.x, wv.w, a03);
    a10 = fmaf(xv.y, wv.x, a10); a11 = fmaf(xv.y, wv.y, a11);
    a12 = fmaf(xv.y, wv.z, a12); a13 = fmaf(xv.y, wv.w, a13);
    a20 = fmaf(xv.z, wv.x, a20); a21 = fmaf(xv.z, wv.y, a21);
    a22 = fmaf(xv.z, wv.z, a22); a23 = fmaf(xv.z, wv.w, a23);
    a30 = fmaf(xv.w, wv.x, a30); a31 = fmaf(xv.w, wv.y, a31);
    a32 = fmaf(xv.w, wv.z, a32); a33 = fmaf(xv.w, wv.w, a33);
  }
  const int gc = tc * 4;
  int gr = row0 + tr * 4;
  if (gr + 0 < n) { float d = dinv[gr + 0]; *(ushort4*)&Gh[(size_t)(gr + 0) * F + gc] = packh4(a00 * d, a01 * d, a02 * d, a03 * d); }
  if (gr + 1 < n) { float d = dinv[gr + 1]; *(ushort4*)&Gh[(size_t)(gr + 1) * F + gc] = packh4(a10 * d, a11 * d, a12 * d, a13 * d); }
  if (gr + 2 < n) { float d = dinv[gr + 2]; *(ushort4*)&Gh[(size_t)(gr + 2) * F + gc] = packh4(a20 * d, a21 * d, a22 * d, a23 * d); }
  if (gr + 3 < n) { float d = dinv[gr + 3]; *(ushort4*)&Gh[(size_t)(gr + 3) * F + gc] = packh4(a30 * d, a31 * d, a32 * d, a33 * d); }
}

// ---- Same GEMM but fp16 input rows (H16): Gh2 = fp16(dinv .* (H @ W2)) ----
__global__ __launch_bounds__(256) void k_gemm_h2(const unsigned short* __restrict__ H16,
    const float* __restrict__ W, const float* __restrict__ dinv,
    unsigned short* __restrict__ Gh, int n) {
  __shared__ float xst[F * 68];
  __shared__ float wsh[F * F];
  const int tid = threadIdx.x;
  const int row0 = blockIdx.x * 64;
  for (int i = tid * 4; i < F * F; i += 1024)
    *(float4*)&wsh[i] = *(const float4*)&W[i];
  for (int i = tid * 4; i < 64 * F; i += 1024) {
    int r = i >> 6, k = i & 63;
    uint2 hh = make_uint2(0u, 0u);
    if (row0 + r < n) hh = *(const uint2*)&H16[(size_t)(row0 + r) * F + k];
    float2 f0 = __half22float2(*(__half2*)&hh.x);
    float2 f1 = __half22float2(*(__half2*)&hh.y);
    xst[(k + 0) * 68 + r] = f0.x;
    xst[(k + 1) * 68 + r] = f0.y;
    xst[(k + 2) * 68 + r] = f1.x;
    xst[(k + 3) * 68 + r] = f1.y;
  }
  __syncthreads();
  const int tc = tid & 15;
  const int tr = tid >> 4;
  float a00 = 0.f, a01 = 0.f, a02 = 0.f, a03 = 0.f;
  float a10 = 0.f, a11 = 0.f, a12 = 0.f, a13 = 0.f;
  float a20 = 0.f, a21 = 0.f, a22 = 0.f, a23 = 0.f;
  float a30 = 0.f, a31 = 0.f, a32 = 0.f, a33 = 0.f;
  const float* xp = &xst[tr * 4];
  const float* wp = &wsh[tc * 4];
#pragma unroll 8
  for (int k = 0; k < F; ++k) {
    float4 xv = *(const float4*)&xp[k * 68];
    float4 wv = *(const float4*)&wp[k * F];
    a00 = fmaf(xv.x, wv.x, a00); a01 = fmaf(xv.x, wv.y, a01);
    a02 = fmaf(xv.x, wv.z, a02); a03 = fmaf(xv.x, wv.w, a03);
    a10 = fmaf(xv.y, wv.x, a10); a11 = fmaf(xv.y, wv.y, a11);
    a12 = fmaf(xv.y, wv.z, a12); a13 = fmaf(xv.y, wv.w, a13);
    a20 = fmaf(xv.z, wv.x, a20); a21 = fmaf(xv.z, wv.y, a21);
    a22 = fmaf(xv.z, wv.z, a22); a23 = fmaf(xv.z, wv.w, a23);
    a30 = fmaf(xv.w, wv.x, a30); a31 = fmaf(xv.w, wv.y, a31);
    a32 = fmaf(xv.w, wv.z, a32); a33 = fmaf(xv.w, wv.w, a33);
  }
  const int gc = tc * 4;
  int gr = row0 + tr * 4;
  if (gr + 0 < n) { float d = dinv[gr + 0]; *(ushort4*)&Gh[(size_t)(gr + 0) * F + gc] = packh4(a00 * d, a01 * d, a02 * d, a03 * d); }
  if (gr + 1 < n) { float d = dinv[gr + 1]; *(ushort4*)&Gh[(size_t)(gr + 1) * F + gc] = packh4(a10 * d, a11 * d, a12 * d, a13 * d); }
  if (gr + 2 < n) { float d = dinv[gr + 2]; *(ushort4*)&Gh[(size_t)(gr + 2) * F + gc] = packh4(a20 * d, a21 * d, a22 * d, a23 * d); }
  if (gr + 3 < n) { float d = dinv[gr + 3]; *(ushort4*)&Gh[(size_t)(gr + 3) * F + gc] = packh4(a30 * d, a31 * d, a32 * d, a33 * d); }
}

// ---- H16[v] = fp16(relu(dinv[v]*(G[v] + sum_in G[src]) + b)) ----
// 8 lanes/node, 16B per lane, 32 nodes/block; no barriers.
__global__ __launch_bounds__(256) void k_gather_h16(const int* __restrict__ csr_off,
    const int* __restrict__ csr_src, const unsigned short* __restrict__ Gh,
    const float* __restrict__ dinv, const float* __restrict__ b,
    unsigned short* __restrict__ H16, int n) {
  int v = blockIdx.x * 32 + (threadIdx.x >> 3);
  if (v >= n) return;
  int l = threadIdx.x & 7;
  const uint4* Gv = (const uint4*)Gh;
  float a[8] = {0.f, 0.f, 0.f, 0.f, 0.f, 0.f, 0.f, 0.f};
  accmix(a, Gv[(size_t)v * 8 + l]);  // self loop
  gather8(Gv, csr_src, csr_off[v], csr_off[v + 1], l, a);
  float d = dinv[v];
  float4 b0 = *(const float4*)&b[l * 8];
  float4 b1 = *(const float4*)&b[l * 8 + 4];
  ushort4 h0 = packh4(fmaxf(fmaf(a[0], d, b0.x), 0.f), fmaxf(fmaf(a[1], d, b0.y), 0.f),
                      fmaxf(fmaf(a[2], d, b0.z), 0.f), fmaxf(fmaf(a[3], d, b0.w), 0.f));
  ushort4 h1 = packh4(fmaxf(fmaf(a[4], d, b1.x), 0.f), fmaxf(fmaf(a[5], d, b1.y), 0.f),
                      fmaxf(fmaf(a[6], d, b1.z), 0.f), fmaxf(fmaf(a[7], d, b1.w), 0.f));
  *(ushort4*)&H16[(size_t)v * F + l * 8] = h0;
  *(ushort4*)&H16[(size_t)v * F + l * 8 + 4] = h1;
}

// ---- Fused: h = relu(dinv*(gather)+b2); out = h @ Wfc + bfc ----
__global__ __launch_bounds__(256) void k_gather_fc(const int* __restrict__ csr_off,
    const int* __restrict__ csr_src, const unsigned short* __restrict__ Gh,
    const float* __restrict__ dinv, const float* __restrict__ bias,
    const float* __restrict__ Wfc, const float* __restrict__ bfc,
    float* __restrict__ OUT, int n) {
  __shared__ float wsh[F * 9];  // stride 9: spreads banks for the q-loop
  __shared__ float bs[NACT];
  const int tid = threadIdx.x;
  for (int i = tid; i < F * NACT; i += 256) wsh[(i >> 3) * 9 + (i & 7)] = Wfc[i];
  if (tid < NACT) bs[tid] = bfc[tid];
  __syncthreads();
  int v = blockIdx.x * 32 + (tid >> 3);
  int l = tid & 7;
  if (v >= n) return;
  const uint4* Gv = (const uint4*)Gh;
  float a[8] = {0.f, 0.f, 0.f, 0.f, 0.f, 0.f, 0.f, 0.f};
  accmix(a, Gv[(size_t)v * 8 + l]);  // self loop
  gather8(Gv, csr_src, csr_off[v], csr_off[v + 1], l, a);
  float d = dinv[v];
  float q[NACT] = {0.f, 0.f, 0.f, 0.f, 0.f, 0.f, 0.f, 0.f};
#pragma unroll
  for (int jj = 0; jj < 8; ++jj) {
    float h = fmaxf(fmaf(a[jj], d, bias[l * 8 + jj]), 0.f);
    const float* wr = &wsh[(l * 8 + jj) * 9];
#pragma unroll
    for (int aa = 0; aa < NACT; ++aa) q[aa] = fmaf(h, wr[aa], q[aa]);
  }
#pragma unroll
  for (int m = 1; m < 8; m <<= 1) {
#pragma unroll
    for (int aa = 0; aa < NACT; ++aa) q[aa] += __shfl_xor(q[aa], m);
  }
  OUT[(size_t)v * NACT + l] = q[l] + bs[l];
}

extern "C" void kernel_launch(void* const* d_in, const int* in_sizes, int n_in,
                              void* d_out, int out_size, void* d_ws, size_t ws_size,
                              hipStream_t stream) {
  const float* x = (const float*)d_in[0];
  const unsigned int* ew = (const unsigned int*)d_in[1];
  const float* W1 = (const float*)d_in[2];
  const float* b1 = (const float*)d_in[3];
  const float* W2 = (const float*)d_in[4];
  const float* b2 = (const float*)d_in[5];
  const float* Wfc = (const float*)d_in[6];
  const float* bfc = (const float*)d_in[7];
  float* out = (float*)d_out;
  const int n = in_sizes[0] / F;
  const int E = in_sizes[1] / 2;
  const int NB = (n + BNODES - 1) >> BSH;

  char* base = (char*)d_ws;
  size_t off = 0;
  auto alloc = [&](size_t bytes) { void* p = base + off; off += (bytes + 255) & ~(size_t)255; return p; };
  int* flag = (int*)alloc(4);
  int* cursor = (int*)alloc(256 * 4);
  int* bucketBase = (int*)alloc((size_t)(NB + 1) * 4);
  int* csr_off = (int*)alloc((size_t)(n + 1) * 4);
  float* dinv = (float*)alloc((size_t)n * 4);
  unsigned int* slab = (unsigned int*)alloc((size_t)NB * CAP * 4);
  int* csr_src = (int*)alloc((size_t)E * 4);
  unsigned short* Gh1 = (unsigned short*)alloc((size_t)n * F * 2);
  unsigned short* H16 = (unsigned short*)alloc((size_t)n * F * 2);
  unsigned short* Gh2 = (unsigned short*)alloc((size_t)n * F * 2);

  const int gbSc = (E + EPB - 1) / EPB;
  const int gbRow = (n + 63) / 64;
  const int gbGa = (n + 31) / 32;

  hipLaunchKernelGGL(k_init, dim3(1), dim3(256), 0, stream, ew, flag, cursor, E);
  hipLaunchKernelGGL(k_scatterE, dim3(gbSc), dim3(256), 0, stream, ew, flag, cursor, slab, E);
  hipLaunchKernelGGL(k_slabscan, dim3(1), dim3(64), 0, stream, cursor, bucketBase, csr_off, NB, n, E);
  hipLaunchKernelGGL(k_bucketcsr, dim3(NB), dim3(256), 0, stream, slab, bucketBase, csr_off, dinv, csr_src, n);

  // layer 1: GEMM then gather (+ReLU, fp16 out)
  hipLaunchKernelGGL(k_gemm_h, dim3(gbRow), dim3(256), 0, stream, x, W1, dinv, Gh1, n);
  hipLaunchKernelGGL(k_gather_h16, dim3(gbGa), dim3(256), 0, stream, csr_off, csr_src, Gh1, dinv, b1, H16, n);
  // layer 2: GEMM (fp16 in) then fused gather + FC head
  hipLaunchKernelGGL(k_gemm_h2, dim3(gbRow), dim3(256), 0, stream, H16, W2, dinv, Gh2, n);
  hipLaunchKernelGGL(k_gather_fc, dim3(gbGa), dim3(256), 0, stream, csr_off, csr_src, Gh2, dinv, b2, Wfc, bfc, out, n);
}

// Round 8
// 162.797 us; speedup vs baseline: 1.0499x; 1.0499x over previous
//
#include <hip/hip_runtime.h>
#include <hip/hip_fp16.h>

// GCN Q-network: two GCNConv(64->64)+ReLU, then FC(64->8).
// out[v] = dinv[v]*(g[v] + sum_{u->v} g[u]) + b,  g[u] = dinv[u]*(X@W)[u]
// Intermediates fp16 (halves gather bytes). Layer-1 gather + ReLU + layer-2
// GEMM fused (H lives only in LDS); FC head fused into the layer-2 gather.
// Gather accumulation via v_fma_mix_f32 (1 VALU op per feature).
// CSR via bucket partition (512 nodes/bucket), no fp32 atomics.

#define F 64
#define NACT 8
#define BSH 9              // 512 nodes per bucket
#define BNODES 512
#define CAP 10240          // slab capacity per bucket (mean ~8192, sigma ~90)
#define EPB 2048           // edges per scatterE block (256 thr x 8)
#define HS 67              // LDS stride for [k][row] H tile: 67%32=3 -> 2-way banks

// init flag/cursor + sampled dtype detect: int64 edges (values < 2^31) have
// every odd 32-bit word zero; 8192 sampled words of int32 edge data being all
// zero has probability ~0.
__global__ __launch_bounds__(256) void k_init(const unsigned int* __restrict__ w,
    int* flag, int* cursor, int E) {
  if (threadIdx.x == 0) *flag = 1;
  cursor[threadIdx.x] = 0;
  __syncthreads();
  int bad = 0;
  for (int i = threadIdx.x; i < 8192; i += 256) {
    if (i < E && w[2 * i + 1] != 0u) bad = 1;
  }
  if (bad) atomicAnd(flag, 0);
}

__device__ __forceinline__ int edge_row(const unsigned int* w, int flag, int e, int E) {
  return flag ? (int)w[2 * e] : (int)w[e];
}
__device__ __forceinline__ int edge_col(const unsigned int* w, int flag, int e, int E) {
  return flag ? (int)w[2 * E + 2 * e] : (int)w[E + e];
}

// Partition edges into dst-buckets. Packed word: src | (dstLocal << 17).
__global__ __launch_bounds__(256) void k_scatterE(const unsigned int* __restrict__ w,
    const int* __restrict__ flag, int* __restrict__ cursor, unsigned int* __restrict__ slab, int E) {
  __shared__ int hist[256];
  __shared__ int base[256];
  const int tid = threadIdx.x;
  const int fl = *flag;
  hist[tid] = 0;
  __syncthreads();
  int pk[8], bb[8], lr[8];
  const int e0 = blockIdx.x * EPB;
#pragma unroll 8
  for (int j = 0; j < 8; ++j) {
    int e = e0 + j * 256 + tid;
    bb[j] = -1;
    if (e < E) {
      int c = edge_col(w, fl, e, E);
      int s = edge_row(w, fl, e, E);
      int b = c >> BSH;
      pk[j] = (unsigned)s | ((unsigned)(c & (BNODES - 1)) << 17);
      bb[j] = b;
      lr[j] = atomicAdd(&hist[b], 1);
    }
  }
  __syncthreads();
  int h = hist[tid];
  if (h > 0) base[tid] = atomicAdd(&cursor[tid], h);
  __syncthreads();
#pragma unroll 8
  for (int j = 0; j < 8; ++j) {
    if (bb[j] >= 0) {
      slab[(size_t)bb[j] * CAP + base[bb[j]] + lr[j]] = (unsigned)pk[j];
    }
  }
}

// Exclusive scan of per-bucket counts -> bucketBase; csr_off[n] = E.
__global__ __launch_bounds__(64) void k_slabscan(const int* __restrict__ cursor,
    int* __restrict__ bucketBase, int* __restrict__ csr_off, int NB, int n, int E) {
  int t = threadIdx.x;
  int per = (NB + 63) / 64;
  int base = t * per;
  int local = 0;
  for (int i = 0; i < per; ++i) if (base + i < NB) local += cursor[base + i];
  int inc = local;
  for (int off = 1; off < 64; off <<= 1) {
    int vv = __shfl_up(inc, off);
    if (t >= off) inc += vv;
  }
  int run = inc - local;
  for (int i = 0; i < per; ++i) if (base + i < NB) { bucketBase[base + i] = run; run += cursor[base + i]; }
  if (t == 63) { bucketBase[NB] = inc; csr_off[n] = E; }
}

// One block per bucket: LDS count -> scan -> dinv, csr_off, dst-sorted csr_src.
__global__ __launch_bounds__(256) void k_bucketcsr(const unsigned int* __restrict__ slab,
    const int* __restrict__ bucketBase, int* __restrict__ csr_off, float* __restrict__ dinv,
    int* __restrict__ csr_src, int n) {
  __shared__ int cnt[BNODES];
  __shared__ int off[BNODES];
  __shared__ int sA[256], sB[256];
  const int tid = threadIdx.x;
  const int b = blockIdx.x;
  const int csrbeg = bucketBase[b];
  const int cntb = bucketBase[b + 1] - csrbeg;
  const unsigned int* sl = &slab[(size_t)b * CAP];
  cnt[tid] = 0;
  cnt[tid + 256] = 0;
  __syncthreads();
  for (int i = tid; i < cntb; i += 256) {
    atomicAdd(&cnt[sl[i] >> 17], 1);
  }
  __syncthreads();
  int c0 = cnt[2 * tid], c1 = cnt[2 * tid + 1];
  int p = c0 + c1;
  sA[tid] = p;
  __syncthreads();
  int* srcb = sA;
  int* dstb = sB;
  for (int o = 1; o < 256; o <<= 1) {
    int v = srcb[tid];
    if (tid >= o) v += srcb[tid - o];
    __syncthreads();
    dstb[tid] = v;
    __syncthreads();
    int* t2 = srcb; srcb = dstb; dstb = t2;
  }
  int ex2 = srcb[tid] - p;
  off[2 * tid] = ex2;
  off[2 * tid + 1] = ex2 + c0;
  __syncthreads();
  int v0 = (b << BSH) + 2 * tid;
  if (v0 < n) { csr_off[v0] = csrbeg + off[2 * tid]; dinv[v0] = rsqrtf((float)(c0 + 1)); }
  if (v0 + 1 < n) { csr_off[v0 + 1] = csrbeg + off[2 * tid + 1]; dinv[v0 + 1] = rsqrtf((float)(c1 + 1)); }
  __syncthreads();
  for (int i = tid; i < cntb; i += 256) {
    unsigned int pk = sl[i];
    int dl = pk >> 17;
    int pos = atomicAdd(&off[dl], 1);
    csr_src[csrbeg + pos] = (int)(pk & 0x1FFFFu);
  }
}

__device__ __forceinline__ ushort4 packh4(float a, float b, float c, float d) {
  ushort4 r;
  r.x = __half_as_ushort(__float2half_rn(a));
  r.y = __half_as_ushort(__float2half_rn(b));
  r.z = __half_as_ushort(__float2half_rn(c));
  r.w = __half_as_ushort(__float2half_rn(d));
  return r;
}

// a[j] += f32(g.h16[j]) via v_fma_mix_f32 (one VALU op per feature; exact
// f16->f32 promotion, fp32 accumulate -- same rounding as cvt+add).
__device__ __forceinline__ void accmix(float* a, uint4 g) {
  float one = 1.0f;
  asm volatile(
    "v_fma_mix_f32 %0, %9, %8, %0 op_sel:[0,0,0] op_sel_hi:[1,0,0]\n\t"
    "v_fma_mix_f32 %1, %9, %8, %1 op_sel:[1,0,0] op_sel_hi:[1,0,0]\n\t"
    "v_fma_mix_f32 %2, %10, %8, %2 op_sel:[0,0,0] op_sel_hi:[1,0,0]\n\t"
    "v_fma_mix_f32 %3, %10, %8, %3 op_sel:[1,0,0] op_sel_hi:[1,0,0]\n\t"
    "v_fma_mix_f32 %4, %11, %8, %4 op_sel:[0,0,0] op_sel_hi:[1,0,0]\n\t"
    "v_fma_mix_f32 %5, %11, %8, %5 op_sel:[1,0,0] op_sel_hi:[1,0,0]\n\t"
    "v_fma_mix_f32 %6, %12, %8, %6 op_sel:[0,0,0] op_sel_hi:[1,0,0]\n\t"
    "v_fma_mix_f32 %7, %12, %8, %7 op_sel:[1,0,0] op_sel_hi:[1,0,0]"
    : "+v"(a[0]), "+v"(a[1]), "+v"(a[2]), "+v"(a[3]),
      "+v"(a[4]), "+v"(a[5]), "+v"(a[6]), "+v"(a[7])
    : "v"(one), "v"(g.x), "v"(g.y), "v"(g.z), "v"(g.w));
}

// 8-deep unrolled CSR gather of fp16 rows into fp32 acc a[8].
__device__ __forceinline__ void gather8(const uint4* __restrict__ Gv,
    const int* __restrict__ csr_src, int beg, int end, int l, float* a) {
  int j = beg;
  for (; j + 8 <= end; j += 8) {
    uint4 g0 = Gv[(size_t)csr_src[j + 0] * 8 + l];
    uint4 g1 = Gv[(size_t)csr_src[j + 1] * 8 + l];
    uint4 g2 = Gv[(size_t)csr_src[j + 2] * 8 + l];
    uint4 g3 = Gv[(size_t)csr_src[j + 3] * 8 + l];
    uint4 g4 = Gv[(size_t)csr_src[j + 4] * 8 + l];
    uint4 g5 = Gv[(size_t)csr_src[j + 5] * 8 + l];
    uint4 g6 = Gv[(size_t)csr_src[j + 6] * 8 + l];
    uint4 g7 = Gv[(size_t)csr_src[j + 7] * 8 + l];
    accmix(a, g0); accmix(a, g1); accmix(a, g2); accmix(a, g3);
    accmix(a, g4); accmix(a, g5); accmix(a, g6); accmix(a, g7);
  }
  for (; j + 4 <= end; j += 4) {
    uint4 g0 = Gv[(size_t)csr_src[j + 0] * 8 + l];
    uint4 g1 = Gv[(size_t)csr_src[j + 1] * 8 + l];
    uint4 g2 = Gv[(size_t)csr_src[j + 2] * 8 + l];
    uint4 g3 = Gv[(size_t)csr_src[j + 3] * 8 + l];
    accmix(a, g0); accmix(a, g1); accmix(a, g2); accmix(a, g3);
  }
  for (; j < end; ++j) accmix(a, Gv[(size_t)csr_src[j] * 8 + l]);
}

// ---- Gh = fp16(dinv .* (X @ W)), X fp32; 64x64 tile, 4x4 reg tile ----
__global__ __launch_bounds__(256) void k_gemm_h(const float* __restrict__ X, const float* __restrict__ W,
    const float* __restrict__ dinv, unsigned short* __restrict__ Gh, int n) {
  __shared__ float xst[F * 68];  // [k][row], stride 68
  __shared__ float wsh[F * F];   // [k][col]
  const int tid = threadIdx.x;
  const int row0 = blockIdx.x * 64;
  for (int i = tid * 4; i < F * F; i += 1024)
    *(float4*)&wsh[i] = *(const float4*)&W[i];
  for (int i = tid * 4; i < 64 * F; i += 1024) {
    int r = i >> 6, k = i & 63;
    float4 v = make_float4(0.f, 0.f, 0.f, 0.f);
    if (row0 + r < n) v = *(const float4*)&X[(size_t)(row0 + r) * F + k];
    xst[(k + 0) * 68 + r] = v.x;
    xst[(k + 1) * 68 + r] = v.y;
    xst[(k + 2) * 68 + r] = v.z;
    xst[(k + 3) * 68 + r] = v.w;
  }
  __syncthreads();
  const int tc = tid & 15;
  const int tr = tid >> 4;
  float a00 = 0.f, a01 = 0.f, a02 = 0.f, a03 = 0.f;
  float a10 = 0.f, a11 = 0.f, a12 = 0.f, a13 = 0.f;
  float a20 = 0.f, a21 = 0.f, a22 = 0.f, a23 = 0.f;
  float a30 = 0.f, a31 = 0.f, a32 = 0.f, a33 = 0.f;
  const float* xp = &xst[tr * 4];
  const float* wp = &wsh[tc * 4];
#pragma unroll 8
  for (int k = 0; k < F; ++k) {
    float4 xv = *(const float4*)&xp[k * 68];
    float4 wv = *(const float4*)&wp[k * F];
    a00 = fmaf(xv.x, wv.x, a00); a01 = fmaf(xv.x, wv.y, a01);
    a02 = fmaf(xv.x, wv.z, a02); a03 = fmaf(xv.x, wv.w, a03);
    a10 = fmaf(xv.y, wv.x, a10); a11 = fmaf(xv.y, wv.y, a11);
    a12 = fmaf(xv.y, wv.z, a12); a13 = fmaf(xv.y, wv.w, a13);
    a20 = fmaf(xv.z, wv.x, a20); a21 = fmaf(xv.z, wv.y, a21);
    a22 = fmaf(xv.z, wv.z, a22); a23 = fmaf(xv.z, wv.w, a23);
    a30 = fmaf(xv.w, wv.x, a30); a31 = fmaf(xv.w, wv.y, a31);
    a32 = fmaf(xv.w, wv.z, a32); a33 = fmaf(xv.w, wv.w, a33);
  }
  const int gc = tc * 4;
  int gr = row0 + tr * 4;
  if (gr + 0 < n) { float d = dinv[gr + 0]; *(ushort4*)&Gh[(size_t)(gr + 0) * F + gc] = packh4(a00 * d, a01 * d, a02 * d, a03 * d); }
  if (gr + 1 < n) { float d = dinv[gr + 1]; *(ushort4*)&Gh[(size_t)(gr + 1) * F + gc] = packh4(a10 * d, a11 * d, a12 * d, a13 * d); }
  if (gr + 2 < n) { float d = dinv[gr + 2]; *(ushort4*)&Gh[(size_t)(gr + 2) * F + gc] = packh4(a20 * d, a21 * d, a22 * d, a23 * d); }
  if (gr + 3 < n) { float d = dinv[gr + 3]; *(ushort4*)&Gh[(size_t)(gr + 3) * F + gc] = packh4(a30 * d, a31 * d, a32 * d, a33 * d); }
}

// ---- Fused layer-1 gather + ReLU + layer-2 GEMM ----
// 512 threads / 64 nodes per block. Phase A: 8 lanes/node gather Gh1 rows
// (v_fma_mix accumulate), h = relu(dinv*a + b1) -> LDS hst[k][row].
// Phase B: 64x64 GEMM vs LDS W2, 2x4 reg tile, epilogue Gh2 = fp16(dinv*acc).
__global__ __launch_bounds__(512) void k_gather_gemm(const int* __restrict__ csr_off,
    const int* __restrict__ csr_src, const unsigned short* __restrict__ Gh1,
    const float* __restrict__ dinv, const float* __restrict__ bias,
    const float* __restrict__ W2, unsigned short* __restrict__ Gh2, int n) {
  __shared__ float hst[F * HS];  // [k][row]
  __shared__ float wsh[F * F];   // [k][col]
  const int tid = threadIdx.x;
  const int row0 = blockIdx.x * 64;
  // stage W2
  {
    int i = tid * 8;
    *(float4*)&wsh[i] = *(const float4*)&W2[i];
    *(float4*)&wsh[i + 4] = *(const float4*)&W2[i + 4];
  }
  // phase A: gather
  const int ln = tid >> 3;       // node within tile (0..63)
  const int l = tid & 7;         // feature-octet lane
  const int v = row0 + ln;
  float a[8] = {0.f, 0.f, 0.f, 0.f, 0.f, 0.f, 0.f, 0.f};
  if (v < n) {
    const uint4* Gv = (const uint4*)Gh1;
    accmix(a, Gv[(size_t)v * 8 + l]);  // self loop
    gather8(Gv, csr_src, csr_off[v], csr_off[v + 1], l, a);
    float d = dinv[v];
#pragma unroll
    for (int jj = 0; jj < 8; ++jj) {
      float h = fmaxf(fmaf(a[jj], d, bias[l * 8 + jj]), 0.f);
      hst[(l * 8 + jj) * HS + ln] = h;
    }
  } else {
#pragma unroll
    for (int jj = 0; jj < 8; ++jj) hst[(l * 8 + jj) * HS + ln] = 0.f;
  }
  __syncthreads();
  // phase B: GEMM, thread = 2 rows x 4 cols
  const int tc = tid & 15;       // col quad
  const int tr = tid >> 4;       // row pair (0..31)
  const int r0 = 2 * tr;
  float a00 = 0.f, a01 = 0.f, a02 = 0.f, a03 = 0.f;
  float a10 = 0.f, a11 = 0.f, a12 = 0.f, a13 = 0.f;
  const float* wp = &wsh[tc * 4];
#pragma unroll 8
  for (int k = 0; k < F; ++k) {
    float h0 = hst[k * HS + r0];
    float h1 = hst[k * HS + r0 + 1];
    float4 wv = *(const float4*)&wp[k * F];
    a00 = fmaf(h0, wv.x, a00); a01 = fmaf(h0, wv.y, a01);
    a02 = fmaf(h0, wv.z, a02); a03 = fmaf(h0, wv.w, a03);
    a10 = fmaf(h1, wv.x, a10); a11 = fmaf(h1, wv.y, a11);
    a12 = fmaf(h1, wv.z, a12); a13 = fmaf(h1, wv.w, a13);
  }
  const int gc = tc * 4;
  int gr = row0 + r0;
  if (gr < n) { float d = dinv[gr]; *(ushort4*)&Gh2[(size_t)gr * F + gc] = packh4(a00 * d, a01 * d, a02 * d, a03 * d); }
  if (gr + 1 < n) { float d = dinv[gr + 1]; *(ushort4*)&Gh2[(size_t)(gr + 1) * F + gc] = packh4(a10 * d, a11 * d, a12 * d, a13 * d); }
}

// ---- Fused: h = relu(dinv*(gather)+b2); out = h @ Wfc + bfc ----
__global__ __launch_bounds__(256) void k_gather_fc(const int* __restrict__ csr_off,
    const int* __restrict__ csr_src, const unsigned short* __restrict__ Gh,
    const float* __restrict__ dinv, const float* __restrict__ bias,
    const float* __restrict__ Wfc, const float* __restrict__ bfc,
    float* __restrict__ OUT, int n) {
  __shared__ float wsh[F * 9];  // stride 9: spreads banks for the q-loop
  __shared__ float bs[NACT];
  const int tid = threadIdx.x;
  for (int i = tid; i < F * NACT; i += 256) wsh[(i >> 3) * 9 + (i & 7)] = Wfc[i];
  if (tid < NACT) bs[tid] = bfc[tid];
  __syncthreads();
  int v = blockIdx.x * 32 + (tid >> 3);
  int l = tid & 7;
  if (v >= n) return;
  const uint4* Gv = (const uint4*)Gh;
  float a[8] = {0.f, 0.f, 0.f, 0.f, 0.f, 0.f, 0.f, 0.f};
  accmix(a, Gv[(size_t)v * 8 + l]);  // self loop
  gather8(Gv, csr_src, csr_off[v], csr_off[v + 1], l, a);
  float d = dinv[v];
  float q[NACT] = {0.f, 0.f, 0.f, 0.f, 0.f, 0.f, 0.f, 0.f};
#pragma unroll
  for (int jj = 0; jj < 8; ++jj) {
    float h = fmaxf(fmaf(a[jj], d, bias[l * 8 + jj]), 0.f);
    const float* wr = &wsh[(l * 8 + jj) * 9];
#pragma unroll
    for (int aa = 0; aa < NACT; ++aa) q[aa] = fmaf(h, wr[aa], q[aa]);
  }
#pragma unroll
  for (int m = 1; m < 8; m <<= 1) {
#pragma unroll
    for (int aa = 0; aa < NACT; ++aa) q[aa] += __shfl_xor(q[aa], m);
  }
  OUT[(size_t)v * NACT + l] = q[l] + bs[l];
}

extern "C" void kernel_launch(void* const* d_in, const int* in_sizes, int n_in,
                              void* d_out, int out_size, void* d_ws, size_t ws_size,
                              hipStream_t stream) {
  const float* x = (const float*)d_in[0];
  const unsigned int* ew = (const unsigned int*)d_in[1];
  const float* W1 = (const float*)d_in[2];
  const float* b1 = (const float*)d_in[3];
  const float* W2 = (const float*)d_in[4];
  const float* b2 = (const float*)d_in[5];
  const float* Wfc = (const float*)d_in[6];
  const float* bfc = (const float*)d_in[7];
  float* out = (float*)d_out;
  const int n = in_sizes[0] / F;
  const int E = in_sizes[1] / 2;
  const int NB = (n + BNODES - 1) >> BSH;

  char* base = (char*)d_ws;
  size_t off = 0;
  auto alloc = [&](size_t bytes) { void* p = base + off; off += (bytes + 255) & ~(size_t)255; return p; };
  int* flag = (int*)alloc(4);
  int* cursor = (int*)alloc(256 * 4);
  int* bucketBase = (int*)alloc((size_t)(NB + 1) * 4);
  int* csr_off = (int*)alloc((size_t)(n + 1) * 4);
  float* dinv = (float*)alloc((size_t)n * 4);
  unsigned int* slab = (unsigned int*)alloc((size_t)NB * CAP * 4);
  int* csr_src = (int*)alloc((size_t)E * 4);
  unsigned short* Gh1 = (unsigned short*)alloc((size_t)n * F * 2);
  unsigned short* Gh2 = (unsigned short*)alloc((size_t)n * F * 2);

  const int gbSc = (E + EPB - 1) / EPB;
  const int gbRow = (n + 63) / 64;
  const int gbGa = (n + 31) / 32;

  hipLaunchKernelGGL(k_init, dim3(1), dim3(256), 0, stream, ew, flag, cursor, E);
  hipLaunchKernelGGL(k_scatterE, dim3(gbSc), dim3(256), 0, stream, ew, flag, cursor, slab, E);
  hipLaunchKernelGGL(k_slabscan, dim3(1), dim3(64), 0, stream, cursor, bucketBase, csr_off, NB, n, E);
  hipLaunchKernelGGL(k_bucketcsr, dim3(NB), dim3(256), 0, stream, slab, bucketBase, csr_off, dinv, csr_src, n);

  // layer 1 GEMM
  hipLaunchKernelGGL(k_gemm_h, dim3(gbRow), dim3(256), 0, stream, x, W1, dinv, Gh1, n);
  // fused layer-1 gather + ReLU + layer-2 GEMM
  hipLaunchKernelGGL(k_gather_gemm, dim3(gbRow), dim3(512), 0, stream, csr_off, csr_src, Gh1, dinv, b1, W2, Gh2, n);
  // fused layer-2 gather + FC head
  hipLaunchKernelGGL(k_gather_fc, dim3(gbGa), dim3(256), 0, stream, csr_off, csr_src, Gh2, dinv, b2, Wfc, bfc, out, n);
}